// Round 7
// baseline (3905.740 us; speedup 1.0000x reference)
//
#include <hip/hip_runtime.h>
#include <hip/hip_cooperative_groups.h>
#include <math.h>

namespace cg = cooperative_groups;

#define BATCH 8192
#define FEAT  64
#define HID   1024
#define NSTEPS 8
#define RM    32            // batch rows per block
#define NBLK  (BATCH / RM)  // 256 blocks = 1 per CU (LDS-limited)

typedef __attribute__((ext_vector_type(8))) short bf16x8;
typedef __attribute__((ext_vector_type(4))) float f32x4;
typedef __attribute__((ext_vector_type(2))) unsigned int u32x2;
typedef unsigned short u16;
typedef unsigned int u32;

__device__ __forceinline__ float bf2f(u16 u) {
    u32 v = ((u32)u) << 16;
    return __builtin_bit_cast(float, v);
}
__device__ __forceinline__ u16 f2bf(float f) {
    u32 v = __builtin_bit_cast(u32, f);
    v += 0x7FFFu + ((v >> 16) & 1u);
    return (u16)(v >> 16);
}
__device__ __forceinline__ u32 pack2(u16 a, u16 b) { return (u32)a | ((u32)b << 16); }

// storage swizzle: within each 64-elem window of row m, 8-elem slot s -> s^(m&7)
__device__ __host__ __forceinline__ size_t swz_off(int m, int k, int K) {
    int s = (k >> 3) & 7;
    return (size_t)m * K + (k & ~63) + (((s ^ m) & 7) << 3) + (k & 7);
}
__device__ __forceinline__ int ldso(int m, int j) {   // 1024-wide LDS tiles
    return m * HID + (j & ~63) + (((((j >> 3)) ^ m) & 7) << 3) + (j & 7);
}
__device__ __forceinline__ int lds64(int m, int f) {  // 64-wide LDS tiles
    return m * 64 + (((((f >> 3)) ^ m) & 7) << 3) + (f & 7);
}
__device__ __forceinline__ float tanh_fast(float x) {
    x = fminf(20.f, fmaxf(-20.f, x));
    float e = __builtin_amdgcn_exp2f(x * 2.8853900817779268f); // e^(2x)
    return 1.f - 2.f * __builtin_amdgcn_rcpf(e + 1.f);
}

__global__ __launch_bounds__(512, 2)
void ffjord_mega(const float* __restrict__ x,
                 const float* __restrict__ eps,
                 const u16* __restrict__ w1tb,   // [1024][64]  = W1[:64]^T  swz
                 const float* __restrict__ w1x,  // W1 row 64 (t coeff) fp32 [1024]
                 const float* __restrict__ b1,
                 const u16* __restrict__ w2t,    // [1024][1024] = W2^T swz
                 const float* __restrict__ b2,
                 const u16* __restrict__ w3n,    // [1024][64]  = W3    swz
                 const u16* __restrict__ w3t,    // [64][1024]  = W3^T  swz
                 const float* __restrict__ b3,
                 float* __restrict__ outp)
{
    __shared__ __align__(16) u16 h1s[RM * HID];   // h1, overwritten with h2
    __shared__ __align__(16) u16 mes[RM * HID];   // me = (1-h1^2)*E
    __shared__ __align__(16) u16 xins[RM * 64];   // current xin (bf16, swz)
    __shared__ __align__(16) u16 epss[RM * 64];   // eps tile (bf16, swz)
    __shared__ float red[RM * 33];                // trace reduction

    cg::grid_group gg = cg::this_grid();

    const int tid = threadIdx.x;
    const int wv = tid >> 6, lane = tid & 63;
    const int l15 = lane & 15, l4 = lane >> 4;
    const int m0 = blockIdx.x * RM;

    // per-thread state ownership (matches G3 C/D layout):
    const int sm = (wv & 1) * 16 + l15;         // batch row within tile
    const int sf = (wv >> 1) * 16 + l4 * 4;     // 4 consecutive features

    float yxr[4], axr[4];
    {
        f32x4 xv = *(const f32x4*)(x + (size_t)(m0 + sm) * FEAT + sf);
        f32x4 ev = *(const f32x4*)(eps + (size_t)(m0 + sm) * FEAT + sf);
#pragma unroll
        for (int r = 0; r < 4; r++) yxr[r] = xv[r];
        u32x2 px = { pack2(f2bf(xv[0]), f2bf(xv[1])), pack2(f2bf(xv[2]), f2bf(xv[3])) };
        u32x2 pe = { pack2(f2bf(ev[0]), f2bf(ev[1])), pack2(f2bf(ev[2]), f2bf(ev[3])) };
        *(u32x2*)&xins[lds64(sm, sf)] = px;
        *(u32x2*)&epss[lds64(sm, sf)] = pe;
    }
    float yl = 0.f, al = 0.f;
    __syncthreads();

    // ---- precompute (constant across all evals): E = eps@W1[:64], g3 = eps@W3^T ----
    u32x2 E_reg[8][2], g3_reg[8][2];
#pragma unroll
    for (int jj = 0; jj < 8; jj++) {
        const int rw = (wv * 8 + jj) * 16 + l15;
        const char* p1 = (const char*)w1tb + rw * 128;
        const char* p3 = (const char*)w3n + rw * 128;
#pragma unroll
        for (int mt = 0; mt < 2; mt++) {
            f32x4 ae = {}, ag = {};
#pragma unroll
            for (int ks = 0; ks < 2; ks++) {
                const int so = (((((ks << 2) | l4) ^ rw) & 7) << 4);
                bf16x8 be = *(const bf16x8*)&epss[lds64(mt * 16 + l15, ks * 32 + l4 * 8)];
                bf16x8 a1 = *(const bf16x8*)(p1 + so);
                bf16x8 a3 = *(const bf16x8*)(p3 + so);
                ae = __builtin_amdgcn_mfma_f32_16x16x32_bf16(a1, be, ae, 0, 0, 0);
                ag = __builtin_amdgcn_mfma_f32_16x16x32_bf16(a3, be, ag, 0, 0, 0);
            }
            E_reg[jj][mt] = (u32x2){ pack2(f2bf(ae[0]), f2bf(ae[1])),
                                     pack2(f2bf(ae[2]), f2bf(ae[3])) };
            g3_reg[jj][mt] = (u32x2){ pack2(f2bf(ag[0]), f2bf(ag[1])),
                                      pack2(f2bf(ag[2]), f2bf(ag[3])) };
        }
    }

    const float h = 1.f / NSTEPS, h6 = h / 6.f;

    f32x4 acc2[8][2], acc5[8][2];
    bf16x8 aA[8], aB[8], bA[2], bB[2], mA[2], mB[2];

    auto w2addr = [&](int jj, int ks) -> const char* {
        int row = (wv * 8 + jj) * 16 + l15;
        return (const char*)w2t + (size_t)row * 2048 + ((ks >> 1) << 7)
               + (((((ks << 2) | l4) ^ row) & 7) << 4);
    };
    auto loadA = [&](bf16x8 (&dst)[8], int ks) {
#pragma unroll
        for (int jj = 0; jj < 8; jj++) dst[jj] = *(const bf16x8*)w2addr(jj, ks);
    };
    auto loadB2 = [&](bf16x8 (&d1)[2], bf16x8 (&d2)[2], int ks) {
#pragma unroll
        for (int mt = 0; mt < 2; mt++) {
            const int off = ldso(mt * 16 + l15, ks * 32 + l4 * 8);
            d1[mt] = *(const bf16x8*)&h1s[off];
            d2[mt] = *(const bf16x8*)&mes[off];
        }
    };
    auto mfma32 = [&](bf16x8 (&a)[8], bf16x8 (&b1v)[2], bf16x8 (&b2v)[2]) {
#pragma unroll
        for (int jj = 0; jj < 8; jj++) {
#pragma unroll
            for (int mt = 0; mt < 2; mt++)
                acc2[jj][mt] = __builtin_amdgcn_mfma_f32_16x16x32_bf16(
                    a[jj], b1v[mt], acc2[jj][mt], 0, 0, 0);
#pragma unroll
            for (int mt = 0; mt < 2; mt++)
                acc5[jj][mt] = __builtin_amdgcn_mfma_f32_16x16x32_bf16(
                    a[jj], b2v[mt], acc5[jj][mt], 0, 0, 0);
        }
    };

    for (int s = 0; s < NSTEPS; s++) {
        for (int st = 0; st < 4; st++) {
            const float ts = s * h + ((st == 1 || st == 2) ? 0.5f * h : (st == 3 ? h : 0.f));

            // ---- G1: h1 = tanh(W1^T@xin^T + b1 + t*w1x) -> h1s; me = (1-h1^2)*E -> mes ----
#pragma unroll
            for (int jj = 0; jj < 8; jj++) {
                const int jr = (wv * 8 + jj) * 16;
                const int rw = jr + l15;
                const char* p1 = (const char*)w1tb + rw * 128;
                f32x4 bb = *(const f32x4*)(b1 + jr + l4 * 4);
                f32x4 wt = *(const f32x4*)(w1x + jr + l4 * 4);
#pragma unroll
                for (int mt = 0; mt < 2; mt++) {
                    f32x4 a1 = {};
#pragma unroll
                    for (int ks = 0; ks < 2; ks++) {
                        const int k0 = ks * 32 + l4 * 8;
                        bf16x8 a = *(const bf16x8*)(p1 + (((((ks << 2) | l4) ^ rw) & 7) << 4));
                        bf16x8 b = *(const bf16x8*)&xins[lds64(mt * 16 + l15, k0)];
                        a1 = __builtin_amdgcn_mfma_f32_16x16x32_bf16(a, b, a1, 0, 0, 0);
                    }
                    float h1v[4], mev[4];
                    u32x2 Ew = E_reg[jj][mt];
                    float Ev[4] = { bf2f((u16)(Ew[0] & 0xffff)), bf2f((u16)(Ew[0] >> 16)),
                                    bf2f((u16)(Ew[1] & 0xffff)), bf2f((u16)(Ew[1] >> 16)) };
#pragma unroll
                    for (int r = 0; r < 4; r++) {
                        h1v[r] = tanh_fast(a1[r] + bb[r] + ts * wt[r]);
                        mev[r] = (1.f - h1v[r] * h1v[r]) * Ev[r];
                    }
                    const int off = ldso(mt * 16 + l15, jr + l4 * 4);
                    *(u32x2*)&h1s[off] = (u32x2){ pack2(f2bf(h1v[0]), f2bf(h1v[1])),
                                                  pack2(f2bf(h1v[2]), f2bf(h1v[3])) };
                    *(u32x2*)&mes[off] = (u32x2){ pack2(f2bf(mev[0]), f2bf(mev[1])),
                                                  pack2(f2bf(mev[2]), f2bf(mev[3])) };
                }
            }
            // block barrier + cross-block alignment before the shared w2t stream
            gg.sync();

            // ---- fused G2+P5: one pass over w2t; acc2 = W2^T@h1^T, acc5 = W2^T@me^T ----
#pragma unroll
            for (int jj = 0; jj < 8; jj++)
#pragma unroll
                for (int mt = 0; mt < 2; mt++) { acc2[jj][mt] = (f32x4){}; acc5[jj][mt] = (f32x4){}; }
            loadA(aA, 0); loadB2(bA, mA, 0);
            for (int ks = 0; ks < 32; ks += 2) {
                loadA(aB, ks + 1); loadB2(bB, mB, ks + 1);
                mfma32(aA, bA, mA);
                if (ks + 2 < 32) { loadA(aA, ks + 2); loadB2(bA, mA, ks + 2); }
                mfma32(aB, bB, mB);
            }
            __syncthreads();  // B2a: h1s/mes fully consumed by all waves

            // ---- epilogue: h2 = tanh(acc2+b2) -> h1s (reuse); trace += acc5 . g3*(1-h2^2) ----
            {
                float ts0 = 0.f, ts1 = 0.f;
#pragma unroll
                for (int jj = 0; jj < 8; jj++) {
                    const int jr = (wv * 8 + jj) * 16;
                    f32x4 bb = *(const f32x4*)(b2 + jr + l4 * 4);
#pragma unroll
                    for (int mt = 0; mt < 2; mt++) {
                        u32x2 gw = g3_reg[jj][mt];
                        float gv[4] = { bf2f((u16)(gw[0] & 0xffff)), bf2f((u16)(gw[0] >> 16)),
                                        bf2f((u16)(gw[1] & 0xffff)), bf2f((u16)(gw[1] >> 16)) };
                        float h2v[4], d = 0.f;
#pragma unroll
                        for (int r = 0; r < 4; r++) {
                            h2v[r] = tanh_fast(acc2[jj][mt][r] + bb[r]);
                            d += acc5[jj][mt][r] * gv[r] * (1.f - h2v[r] * h2v[r]);
                        }
                        const int off = ldso(mt * 16 + l15, jr + l4 * 4);
                        *(u32x2*)&h1s[off] = (u32x2){ pack2(f2bf(h2v[0]), f2bf(h2v[1])),
                                                      pack2(f2bf(h2v[2]), f2bf(h2v[3])) };
                        if (mt == 0) ts0 += d; else ts1 += d;
                    }
                }
                red[l15 * 33 + wv * 4 + l4] = ts0;
                red[(16 + l15) * 33 + wv * 4 + l4] = ts1;
            }
            __syncthreads();  // B2b: h2 (in h1s) + red ready

            // ---- G3: dx^T = W3^T @ h2^T (1 tile/wave, pipelined) ----
            f32x4 acc3 = {};
            {
                const int row3 = (wv >> 1) * 16 + l15;
                const int mt3 = wv & 1;
                auto a3addr = [&](int ks) -> const char* {
                    return (const char*)w3t + (size_t)row3 * 2048 + ((ks >> 1) << 7)
                           + (((((ks << 2) | l4) ^ row3) & 7) << 4);
                };
                bf16x8 ga = *(const bf16x8*)a3addr(0);
                for (int ks = 0; ks < 32; ks += 2) {
                    bf16x8 gb = *(const bf16x8*)a3addr(ks + 1);
                    bf16x8 hb0 = *(const bf16x8*)&h1s[ldso(mt3 * 16 + l15, ks * 32 + l4 * 8)];
                    acc3 = __builtin_amdgcn_mfma_f32_16x16x32_bf16(ga, hb0, acc3, 0, 0, 0);
                    if (ks + 2 < 32) ga = *(const bf16x8*)a3addr(ks + 2);
                    bf16x8 hb1 = *(const bf16x8*)&h1s[ldso(mt3 * 16 + l15, (ks + 1) * 32 + l4 * 8)];
                    acc3 = __builtin_amdgcn_mfma_f32_16x16x32_bf16(gb, hb1, acc3, 0, 0, 0);
                }
            }

            // ---- RK4 combine (in-register state) ----
            {
                const float wacc = (st == 1 || st == 2) ? 2.f : 1.f;
                const float wtmp = (st < 2) ? 0.5f * h : h;
                f32x4 b3v = *(const f32x4*)(b3 + sf);
                float nx[4];
#pragma unroll
                for (int r = 0; r < 4; r++) {
                    float d = acc3[r] + b3v[r];
                    axr[r] = (st == 0 ? 0.f : axr[r]) + wacc * d;
                    if (st == 3) { yxr[r] += h6 * axr[r]; nx[r] = yxr[r]; }
                    else nx[r] = yxr[r] + wtmp * d;
                }
                u32x2 px = { pack2(f2bf(nx[0]), f2bf(nx[1])), pack2(f2bf(nx[2]), f2bf(nx[3])) };
                *(u32x2*)&xins[lds64(sm, sf)] = px;
                if (tid < RM) {
                    float tr = 0.f;
#pragma unroll
                    for (int c = 0; c < 32; c++) tr += red[tid * 33 + c];
                    al = (st == 0 ? 0.f : al) + wacc * (-tr);
                    if (st == 3) yl += h6 * al;
                }
            }
            __syncthreads();  // B5: xins ready; h1s/mes free for next G1
        }
    }

    // ---- output ----
    {
        f32x4 zv = { yxr[0], yxr[1], yxr[2], yxr[3] };
        *(f32x4*)(outp + (size_t)(m0 + sm) * FEAT + sf) = zv;
        if (tid < RM) outp[(size_t)BATCH * FEAT + m0 + tid] = yl;
    }
}

// ---- weight prep (once per call; tiny) ----
__global__ void cast_bf(const float* __restrict__ in, u16* __restrict__ out,
                        int n, int W)
{
    int i = blockIdx.x * 256 + threadIdx.x;
    if (i < n) out[swz_off(i / W, i % W, W)] = f2bf(in[i]);
}

// in [R'][C'] fp32 -> out [C'][R'] bf16 swizzled
__global__ void transpose_cast(const float* __restrict__ in, u16* __restrict__ out,
                               int R, int C)
{
    __shared__ float t[32][33];
    int bx = blockIdx.x * 32, by = blockIdx.y * 32;
    int tx = threadIdx.x, ty = threadIdx.y;  // block (32,8)
    for (int i = 0; i < 32; i += 8)
        t[ty + i][tx] = in[(size_t)(by + ty + i) * C + bx + tx];
    __syncthreads();
    for (int i = 0; i < 32; i += 8)
        out[swz_off(bx + ty + i, by + tx, R)] = f2bf(t[tx][ty + i]);
}

extern "C" void kernel_launch(void* const* d_in, const int* in_sizes, int n_in,
                              void* d_out, int out_size, void* d_ws, size_t ws_size,
                              hipStream_t stream)
{
    const float* x   = (const float*)d_in[0];
    const float* W1  = (const float*)d_in[1];
    const float* b1  = (const float*)d_in[2];
    const float* W2  = (const float*)d_in[3];
    const float* b2  = (const float*)d_in[4];
    const float* W3  = (const float*)d_in[5];
    const float* b3  = (const float*)d_in[6];
    const float* eps = (const float*)d_in[7];
    float* out = (float*)d_out;

    char* ws = (char*)d_ws;
    size_t o = 0;
    auto alloc = [&](size_t bytes) { char* p = ws + o; o += (bytes + 255) & ~(size_t)255; return p; };

    u16* w1tb = (u16*)alloc((size_t)HID * FEAT * 2);   // [1024][64] W1[:64]^T
    u16* w2t  = (u16*)alloc((size_t)HID * HID * 2);    // W2^T
    u16* w3n  = (u16*)alloc((size_t)HID * FEAT * 2);   // [1024][64] W3
    u16* w3t  = (u16*)alloc((size_t)FEAT * HID * 2);   // [64][1024] W3^T

    const dim3 blk(256);
    cast_bf<<<dim3((HID * FEAT + 255) / 256), blk, 0, stream>>>(W3, w3n, HID * FEAT, FEAT);
    transpose_cast<<<dim3(HID / 32, HID / 32), dim3(32, 8), 0, stream>>>(W2, w2t, HID, HID);
    transpose_cast<<<dim3(HID / 32, FEAT / 32), dim3(32, 8), 0, stream>>>(W1, w1tb, FEAT, HID);
    transpose_cast<<<dim3(FEAT / 32, HID / 32), dim3(32, 8), 0, stream>>>(W3, w3t, HID, FEAT);

    const float* w1x = W1 + (size_t)FEAT * HID;
    void* args[] = { (void*)&x, (void*)&eps, (void*)&w1tb, (void*)&w1x, (void*)&b1,
                     (void*)&w2t, (void*)&b2, (void*)&w3n, (void*)&w3t, (void*)&b3,
                     (void*)&out };
    hipLaunchCooperativeKernel((void*)ffjord_mega, dim3(NBLK), dim3(512), args, 0, stream);
}

// Round 8
// 2719.259 us; speedup vs baseline: 1.4363x; 1.4363x over previous
//
#include <hip/hip_runtime.h>
#include <math.h>

#define BATCH 8192
#define FEAT  64
#define HID   1024
#define NSTEPS 8

typedef __attribute__((ext_vector_type(8))) short bf16x8;
typedef __attribute__((ext_vector_type(4))) float f32x4;
typedef unsigned short u16;
typedef unsigned int u32;

__device__ __forceinline__ float bf2f(u16 u) {
    u32 v = ((u32)u) << 16;
    return __builtin_bit_cast(float, v);
}
__device__ __forceinline__ u16 f2bf(float f) {
    u32 v = __builtin_bit_cast(u32, f);
    v += 0x7FFFu + ((v >> 16) & 1u);
    return (u16)(v >> 16);
}
// storage swizzle: within each 64-elem (128B) window of row m, 16B slot s -> s^(m&7).
__device__ __host__ __forceinline__ size_t swz_off(int m, int k, int K) {
    int s = (k >> 3) & 7;
    return (size_t)m * K + (k & ~63) + (((s ^ m) & 7) << 3) + (k & 7);
}
// 8-elem-slot granular address (gs = global slot index = col/8)
__device__ __forceinline__ size_t swz_slot(int m, int gs, int N) {
    return (size_t)m * N + (((gs & ~7) | ((gs & 7) ^ (m & 7))) << 3);
}
__device__ __forceinline__ float tanh_fast(float x) {
    x = fminf(20.f, fmaxf(-20.f, x));
    float e = __builtin_amdgcn_exp2f(x * 2.8853900817779268f); // e^(2x)
    return 1.f - 2.f * __builtin_amdgcn_rcpf(e + 1.f);
}
__device__ __forceinline__ void gload16(void* lds, const void* g) {
    __builtin_amdgcn_global_load_lds(
        (const __attribute__((address_space(1))) unsigned int*)g,
        (__attribute__((address_space(3))) unsigned int*)lds,
        16, 0, 0);
}

// ---- shared K-loop (round-4, refchecked): BM=128, BK=64, 256 threads,
// 4 waves 2x2, double-buffered global_load_lds, 2-phase prefetch. ----
template<int BN>
__device__ __forceinline__ void kloop(const u16* __restrict__ A,
                                      const u16* __restrict__ Bt,
                                      int K, int m0, int n0, int kb, int ntiles,
                                      char* __restrict__ smem,
                                      f32x4 (&acc)[4][BN / 32])
{
    constexpr int FN = BN / 32;
    const int tid = threadIdx.x, wv = tid >> 6, lane = tid & 63;
    const int l15 = lane & 15, l4 = lane >> 4;
    const int wr = wv >> 1, wc = wv & 1;
    const int Lb = tid * 16;

    auto stage = [&](int buf, int kt) {
        char* Asb = smem + buf * 16384;
        char* Bsb = smem + 32768 + buf * (BN * 128);
#pragma unroll
        for (int q = 0; q < 4; q++) {
            int L = q * 4096 + Lb;
            int row = L >> 7, colb = L & 127;
            gload16(Asb + L, (const char*)A + ((size_t)(m0 + row) * K + kt) * 2 + colb);
        }
#pragma unroll
        for (int q = 0; q < BN / 32; q++) {
            int L = q * 4096 + Lb;
            int row = L >> 7, colb = L & 127;
            gload16(Bsb + L, (const char*)Bt + ((size_t)(n0 + row) * K + kt) * 2 + colb);
        }
    };

    stage(0, kb);
    __syncthreads();
    int buf = 0;
    for (int t = 0; t < ntiles; t++) {
        if (t + 1 < ntiles) stage(buf ^ 1, kb + (t + 1) * 64);
        const char* Asb = smem + buf * 16384;
        const char* Bsb = smem + 32768 + buf * (BN * 128);
#pragma unroll
        for (int ks = 0; ks < 2; ks++) {
            bf16x8 af[4], bfr[FN];
#pragma unroll
            for (int mi = 0; mi < 4; mi++) {
                int r = wr * 64 + mi * 16 + l15;
                af[mi] = *(const bf16x8*)(Asb + r * 128 + ((((ks << 2) | l4) ^ (r & 7)) << 4));
            }
#pragma unroll
            for (int nj = 0; nj < FN; nj++) {
                int c = wc * (FN * 16) + nj * 16 + l15;
                bfr[nj] = *(const bf16x8*)(Bsb + c * 128 + ((((ks << 2) | l4) ^ (c & 7)) << 4));
            }
#pragma unroll
            for (int mi = 0; mi < 4; mi++)
#pragma unroll
                for (int nj = 0; nj < FN; nj++)
                    acc[mi][nj] = __builtin_amdgcn_mfma_f32_16x16x32_bf16(
                        af[mi], bfr[nj], acc[mi][nj], 0, 0, 0);
        }
        __syncthreads();
        buf ^= 1;
    }
}

// MODE 0: Cb = bf16(acc)                                  (g3 / E precompute)
// MODE 1: h1=tanh(acc+bias+t*bias2)->Cb; Cb2=aux*(1-h1^2) (G1 -> h1, me; aux=E)
template<int MODE>
__global__ __launch_bounds__(256)
void mfma_gemm(const u16* __restrict__ A, int K,
               const u16* __restrict__ Bt, int N,
               u16* __restrict__ Cb,
               const float* __restrict__ bias, const float* __restrict__ bias2,
               float tval,
               const u16* __restrict__ auxb, u16* __restrict__ Cb2)
{
    __shared__ __align__(16) char smem[65536];
    const int m0 = blockIdx.y * 128, n0 = blockIdx.x * 128;
    f32x4 acc[4][4] = {};
    kloop<128>(A, Bt, K, m0, n0, 0, K / 64, smem, acc);

    const int tid = threadIdx.x, wv = tid >> 6, lane = tid & 63;
    const int l15 = lane & 15, l4 = lane >> 4;
    const int wr = wv >> 1, wc = wv & 1;
    float* ep = (float*)smem;               // [128][34]
    const int erow = tid >> 1, ehalf = tid & 1;
    const int gm = m0 + erow;
#pragma unroll
    for (int c = 0; c < 4; c++) {
        __syncthreads();
        if (wc == (c >> 1)) {
            int njb = (c & 1) * 2;
#pragma unroll
            for (int mi = 0; mi < 4; mi++)
#pragma unroll
                for (int jj = 0; jj < 2; jj++)
#pragma unroll
                    for (int r = 0; r < 4; r++) {
                        int row = wr * 64 + mi * 16 + l4 * 4 + r;
                        ep[row * 34 + jj * 16 + l15] = acc[mi][njb + jj][r];
                    }
        }
        __syncthreads();
        float v[16];
#pragma unroll
        for (int j = 0; j < 16; j++) v[j] = ep[erow * 34 + ehalf * 16 + j];
        const int kbase = n0 + c * 32 + ehalf * 16;
        const int gsb = (n0 >> 3) + c * 4 + ehalf * 2;
        const size_t idxA = swz_slot(gm, gsb, N);
        const size_t idxB = swz_slot(gm, gsb + 1, N);

        if constexpr (MODE == 0) {
            union { bf16x8 v8; u16 u[8]; } pa, pb;
#pragma unroll
            for (int j = 0; j < 8; j++) { pa.u[j] = f2bf(v[j]); pb.u[j] = f2bf(v[j + 8]); }
            *(bf16x8*)(Cb + idxA) = pa.v8;
            *(bf16x8*)(Cb + idxB) = pb.v8;
        } else {
            union { bf16x8 v8; u16 u[8]; } ha, hb, ga, gb;
            bf16x8 e0 = *(const bf16x8*)(auxb + idxA);
            bf16x8 e1 = *(const bf16x8*)(auxb + idxB);
#pragma unroll
            for (int j = 0; j < 8; j++) {
                float h0 = tanh_fast(v[j] + bias[kbase + j] + tval * bias2[kbase + j]);
                float h1v = tanh_fast(v[j + 8] + bias[kbase + 8 + j] + tval * bias2[kbase + 8 + j]);
                ha.u[j] = f2bf(h0);
                hb.u[j] = f2bf(h1v);
                ga.u[j] = f2bf(bf2f((u16)e0[j]) * (1.f - h0 * h0));
                gb.u[j] = f2bf(bf2f((u16)e1[j]) * (1.f - h1v * h1v));
            }
            *(bf16x8*)(Cb  + idxA) = ha.v8;
            *(bf16x8*)(Cb  + idxB) = hb.v8;
            *(bf16x8*)(Cb2 + idxA) = ga.v8;
            *(bf16x8*)(Cb2 + idxB) = gb.v8;
        }
    }
}

// ---- G2 dual: one w2t pass, two accumulators.
// acc2 = h1 @ W2 (via w2t rows), acc5 = me @ W2.
// Epilogue: h2 = tanh(acc2+b2) -> out; trace partial = sum acc5*g3*(1-h2^2).
__global__ __launch_bounds__(512)
void gemm_dual(const u16* __restrict__ h1, const u16* __restrict__ me,
               const u16* __restrict__ w2t, const u16* __restrict__ g3,
               const float* __restrict__ b2,
               u16* __restrict__ h2, float* __restrict__ trp)
{
    __shared__ __align__(16) char smem[98304];   // A1[2]16K | A2[2]16K | B[2]16K
    const int tid = threadIdx.x, wv = tid >> 6, lane = tid & 63;
    const int l15 = lane & 15, l4 = lane >> 4;
    const int wr = wv >> 2, wc = wv & 3;         // 8 waves: 2M x 4N
    const int m0 = blockIdx.y * 128, n0 = blockIdx.x * 128;
    const int Lb = tid * 16;                     // 512*16B = 8KB per pass

    auto stage = [&](int buf, int kt) {
        char* A1s = smem + buf * 16384;
        char* A2s = smem + 32768 + buf * 16384;
        char* Bs  = smem + 65536 + buf * 16384;
#pragma unroll
        for (int q = 0; q < 2; q++) {
            int L = q * 8192 + Lb;
            int row = L >> 7, colb = L & 127;
            gload16(A1s + L, (const char*)h1 + ((size_t)(m0 + row) * HID + kt) * 2 + colb);
            gload16(A2s + L, (const char*)me + ((size_t)(m0 + row) * HID + kt) * 2 + colb);
            gload16(Bs + L, (const char*)w2t + ((size_t)(n0 + row) * HID + kt) * 2 + colb);
        }
    };

    f32x4 acc2[4][2] = {}, acc5[4][2] = {};
    stage(0, 0);
    __syncthreads();
    int buf = 0;
    for (int t = 0; t < 16; t++) {
        if (t + 1 < 16) stage(buf ^ 1, (t + 1) * 64);
        const char* A1s = smem + buf * 16384;
        const char* A2s = smem + 32768 + buf * 16384;
        const char* Bs  = smem + 65536 + buf * 16384;
#pragma unroll
        for (int ks = 0; ks < 2; ks++) {
            bf16x8 a1f[4], a2f[4], bfr[2];
#pragma unroll
            for (int mi = 0; mi < 4; mi++) {
                int r = wr * 64 + mi * 16 + l15;
                int off = r * 128 + ((((ks << 2) | l4) ^ (r & 7)) << 4);
                a1f[mi] = *(const bf16x8*)(A1s + off);
                a2f[mi] = *(const bf16x8*)(A2s + off);
            }
#pragma unroll
            for (int nj = 0; nj < 2; nj++) {
                int c = wc * 32 + nj * 16 + l15;
                bfr[nj] = *(const bf16x8*)(Bs + c * 128 + ((((ks << 2) | l4) ^ (c & 7)) << 4));
            }
#pragma unroll
            for (int mi = 0; mi < 4; mi++)
#pragma unroll
                for (int nj = 0; nj < 2; nj++) {
                    acc2[mi][nj] = __builtin_amdgcn_mfma_f32_16x16x32_bf16(
                        a1f[mi], bfr[nj], acc2[mi][nj], 0, 0, 0);
                    acc5[mi][nj] = __builtin_amdgcn_mfma_f32_16x16x32_bf16(
                        a2f[mi], bfr[nj], acc5[mi][nj], 0, 0, 0);
                }
        }
        __syncthreads();
        buf ^= 1;
    }

    // ---- epilogue: LDS roundtrip; 512 threads -> (row, 8-col slot) ----
    float* ep2 = (float*)smem;                  // [128][34]
    float* ep5 = (float*)(smem + 17408);        // [128][34]
    float* red = (float*)(smem + 34816);        // [128][4]
    const int erow = tid >> 2, esq = tid & 3;
    const int gm = m0 + erow;
    float tsum = 0.f;
#pragma unroll
    for (int c = 0; c < 4; c++) {
        __syncthreads();
        if (wc == c) {
#pragma unroll
            for (int mi = 0; mi < 4; mi++)
#pragma unroll
                for (int nj = 0; nj < 2; nj++)
#pragma unroll
                    for (int r = 0; r < 4; r++) {
                        int row = wr * 64 + mi * 16 + l4 * 4 + r;
                        ep2[row * 34 + nj * 16 + l15] = acc2[mi][nj][r];
                        ep5[row * 34 + nj * 16 + l15] = acc5[mi][nj][r];
                    }
        }
        __syncthreads();
        float v2[8], v5[8];
#pragma unroll
        for (int j = 0; j < 8; j++) {
            v2[j] = ep2[erow * 34 + esq * 8 + j];
            v5[j] = ep5[erow * 34 + esq * 8 + j];
        }
        const int cb = n0 + c * 32 + esq * 8;
        const int gs = (n0 >> 3) + c * 4 + esq;
        const size_t idx = swz_slot(gm, gs, HID);
        bf16x8 g3v = *(const bf16x8*)(g3 + idx);
        union { bf16x8 v8; u16 u[8]; } hw;
#pragma unroll
        for (int j = 0; j < 8; j++) {
            float hv = tanh_fast(v2[j] + b2[cb + j]);
            hw.u[j] = f2bf(hv);
            tsum += v5[j] * bf2f((u16)g3v[j]) * (1.f - hv * hv);
        }
        *(bf16x8*)(h2 + idx) = hw.v8;
    }
    red[erow * 4 + esq] = tsum;
    __syncthreads();
    if (tid < 128)
        trp[(size_t)blockIdx.x * BATCH + m0 + tid] =
            red[tid * 4] + red[tid * 4 + 1] + red[tid * 4 + 2] + red[tid * 4 + 3];
}

// ---- G3 + RK4 combine: dx = h2 @ W3 + b3 complete per block (no split-K);
// epilogue updates yx/accx/xin_bf and logdet (trace partials from gemm_dual). ----
__global__ __launch_bounds__(256)
void g3_rk4(const u16* __restrict__ h2, const u16* __restrict__ w3t,
            const float* __restrict__ b3, const float* __restrict__ trpart,
            float* __restrict__ yx, float* __restrict__ yld,
            float* __restrict__ accx, float* __restrict__ accld,
            u16* __restrict__ xin_bf, float* __restrict__ outp,
            float wacc, float wtmp, int first, int fin, int last, float h6)
{
    __shared__ __align__(16) char smem[49152];
    const int m0 = blockIdx.x * 128;
    f32x4 acc[4][2] = {};
    kloop<64>(h2, w3t, HID, m0, 0, 0, 16, smem, acc);

    const int tid = threadIdx.x, wv = tid >> 6, lane = tid & 63;
    const int l15 = lane & 15, l4 = lane >> 4;
    const int wr = wv >> 1, wc = wv & 1;

#pragma unroll
    for (int mi = 0; mi < 4; mi++)
#pragma unroll
        for (int nj = 0; nj < 2; nj++)
#pragma unroll
            for (int r = 0; r < 4; r++) {
                int gm = m0 + wr * 64 + mi * 16 + l4 * 4 + r;
                int gn = wc * 32 + nj * 16 + l15;
                size_t i = (size_t)gm * 64 + gn;
                float d = acc[mi][nj][r] + b3[gn];
                float a = (first ? 0.f : accx[i]) + wacc * d;
                accx[i] = a;
                float nx;
                if (fin) { nx = yx[i] + h6 * a; yx[i] = nx; }
                else     { nx = yx[i] + wtmp * d; }
                if (last) outp[i] = nx;
                else      xin_bf[swz_off(gm, gn, 64)] = f2bf(nx);
            }
    if (tid < 128) {
        int m = m0 + tid;
        float tr = 0.f;
#pragma unroll
        for (int nb = 0; nb < 8; nb++) tr += trpart[(size_t)nb * BATCH + m];
        float a = (first ? 0.f : accld[m]) + wacc * (-tr);
        accld[m] = a;
        if (fin) {
            float nl = yld[m] + h6 * a;
            yld[m] = nl;
            if (last) outp[(size_t)BATCH * 64 + m] = nl;
        }
    }
}

__global__ void init_state(const float* __restrict__ x,
                           float* __restrict__ yx, u16* __restrict__ xin_bf,
                           float* __restrict__ yld)
{
    int i = blockIdx.x * 256 + threadIdx.x;
    if (i < BATCH * FEAT) {
        float v = x[i];
        yx[i] = v;
        xin_bf[swz_off(i >> 6, i & 63, 64)] = f2bf(v);
    }
    if (i < BATCH) yld[i] = 0.f;
}

__global__ void cast_bf(const float* __restrict__ in, u16* __restrict__ out,
                        int n, int W)
{
    int i = blockIdx.x * 256 + threadIdx.x;
    if (i < n) out[swz_off(i / W, i % W, W)] = f2bf(in[i]);
}

// in [R'][C'] fp32 -> out [C'][R'] bf16 swizzled
__global__ void transpose_cast(const float* __restrict__ in, u16* __restrict__ out,
                               int R, int C)
{
    __shared__ float t[32][33];
    int bx = blockIdx.x * 32, by = blockIdx.y * 32;
    int tx = threadIdx.x, ty = threadIdx.y;  // block (32,8)
    for (int i = 0; i < 32; i += 8)
        t[ty + i][tx] = in[(size_t)(by + ty + i) * C + bx + tx];
    __syncthreads();
    for (int i = 0; i < 32; i += 8)
        out[swz_off(bx + ty + i, by + tx, R)] = f2bf(t[tx][ty + i]);
}

extern "C" void kernel_launch(void* const* d_in, const int* in_sizes, int n_in,
                              void* d_out, int out_size, void* d_ws, size_t ws_size,
                              hipStream_t stream)
{
    const float* x   = (const float*)d_in[0];
    const float* W1  = (const float*)d_in[1];
    const float* b1  = (const float*)d_in[2];
    const float* W2  = (const float*)d_in[3];
    const float* b2  = (const float*)d_in[4];
    const float* W3  = (const float*)d_in[5];
    const float* b3  = (const float*)d_in[6];
    const float* eps = (const float*)d_in[7];
    float* out = (float*)d_out;

    char* ws = (char*)d_ws;
    size_t o = 0;
    auto alloc = [&](size_t bytes) { char* p = ws + o; o += (bytes + 255) & ~(size_t)255; return p; };

    float* yx     = (float*)alloc((size_t)BATCH * FEAT * 4);
    float* yld    = (float*)alloc(BATCH * 4);
    float* accx   = (float*)alloc((size_t)BATCH * FEAT * 4);
    float* accld  = (float*)alloc(BATCH * 4);
    float* trpart = (float*)alloc((size_t)8 * BATCH * 4);
    u16* xin_bf   = (u16*)alloc((size_t)BATCH * FEAT * 2);
    u16* h1       = (u16*)alloc((size_t)BATCH * HID * 2);
    u16* me       = (u16*)alloc((size_t)BATCH * HID * 2);
    u16* h2       = (u16*)alloc((size_t)BATCH * HID * 2);
    u16* g3       = (u16*)alloc((size_t)BATCH * HID * 2);
    u16* E_bf     = (u16*)alloc((size_t)BATCH * HID * 2);
    u16* eps_bf   = (u16*)alloc((size_t)BATCH * FEAT * 2);
    u16* w1tb     = (u16*)alloc((size_t)HID * FEAT * 2);   // [1024][64] W1[:64]^T
    u16* w2t      = (u16*)alloc((size_t)HID * HID * 2);    // W2^T
    u16* w3_bf    = (u16*)alloc((size_t)HID * FEAT * 2);   // [1024][64] W3
    u16* w3t      = (u16*)alloc((size_t)FEAT * HID * 2);   // [64][1024] W3^T

    const dim3 blk(256);
    const dim3 gBig(HID / 128, BATCH / 128);   // (8, 64)

    // ---- setup (every call; deterministic) ----
    init_state<<<dim3((BATCH * FEAT + 255) / 256), blk, 0, stream>>>(x, yx, xin_bf, yld);
    cast_bf<<<dim3((HID * FEAT + 255) / 256), blk, 0, stream>>>(W3, w3_bf, HID * FEAT, FEAT);
    cast_bf<<<dim3((BATCH * FEAT + 255) / 256), blk, 0, stream>>>(eps, eps_bf, BATCH * FEAT, FEAT);
    transpose_cast<<<dim3(HID / 32, HID / 32), dim3(32, 8), 0, stream>>>(W2, w2t, HID, HID);
    transpose_cast<<<dim3(HID / 32, FEAT / 32), dim3(32, 8), 0, stream>>>(W1, w1tb, FEAT, HID);
    transpose_cast<<<dim3(FEAT / 32, HID / 32), dim3(32, 8), 0, stream>>>(W3, w3t, HID, FEAT);
    // g3 = eps @ W3^T ; E = eps @ W1[:64]   (constant across evals)
    mfma_gemm<0><<<gBig, blk, 0, stream>>>(eps_bf, FEAT, w3_bf, HID,
                                           g3, nullptr, nullptr, 0.f, nullptr, nullptr);
    mfma_gemm<0><<<gBig, blk, 0, stream>>>(eps_bf, FEAT, w1tb, HID,
                                           E_bf, nullptr, nullptr, 0.f, nullptr, nullptr);

    const float h = 1.0f / NSTEPS;
    const float cs[4] = {0.f, 0.5f, 0.5f, 1.f};

    for (int s = 0; s < NSTEPS; s++) {
        float t0 = s * h;
        for (int st = 0; st < 4; st++) {
            float ts = t0 + cs[st] * h;
            // G1: h1 = tanh(xin@W1 + b1 + t*w1x); me = (1-h1^2)*E
            mfma_gemm<1><<<gBig, blk, 0, stream>>>(xin_bf, FEAT, w1tb, HID,
                                                   h1, b1, W1 + (size_t)FEAT * HID, ts,
                                                   E_bf, me);
            // G2 dual: h2 = tanh(h1@W2+b2); trpart = rowsum((me@W2)*g3*(1-h2^2))
            gemm_dual<<<gBig, dim3(512), 0, stream>>>(h1, me, w2t, g3, b2, h2, trpart);
            // G3 + RK4 combine
            float wacc = (st == 1 || st == 2) ? 2.f : 1.f;
            float wtmp = (st == 0 || st == 1) ? h * 0.5f : h;
            g3_rk4<<<dim3(BATCH / 128), blk, 0, stream>>>(h2, w3t, b3, trpart,
                                                          yx, yld, accx, accld,
                                                          xin_bf, out,
                                                          wacc, wtmp,
                                                          (st == 0) ? 1 : 0,
                                                          (st == 3) ? 1 : 0,
                                                          (s == NSTEPS - 1 && st == 3) ? 1 : 0,
                                                          h / 6.f);
        }
    }
}

// Round 9
// 2022.912 us; speedup vs baseline: 1.9308x; 1.3442x over previous
//
#include <hip/hip_runtime.h>
#include <math.h>

#define BATCH 8192
#define FEAT  64
#define HID   1024
#define NSTEPS 8

typedef __attribute__((ext_vector_type(8))) short bf16x8;
typedef __attribute__((ext_vector_type(4))) float f32x4;
typedef unsigned short u16;
typedef unsigned int u32;

__device__ __forceinline__ float bf2f(u16 u) {
    u32 v = ((u32)u) << 16;
    return __builtin_bit_cast(float, v);
}
__device__ __forceinline__ u16 f2bf(float f) {
    u32 v = __builtin_bit_cast(u32, f);
    v += 0x7FFFu + ((v >> 16) & 1u);
    return (u16)(v >> 16);
}
// storage swizzle: within each 64-elem (128B) window of row m, 16B slot s -> s^(m&7).
__device__ __host__ __forceinline__ size_t swz_off(int m, int k, int K) {
    int s = (k >> 3) & 7;
    return (size_t)m * K + (k & ~63) + (((s ^ m) & 7) << 3) + (k & 7);
}
// 8-elem-slot granular address (gs = global slot index = col/8)
__device__ __forceinline__ size_t swz_slot(int m, int gs, int N) {
    return (size_t)m * N + (((gs & ~7) | ((gs & 7) ^ (m & 7))) << 3);
}
__device__ __forceinline__ float tanh_fast(float x) {
    x = fminf(20.f, fmaxf(-20.f, x));
    float e = __builtin_amdgcn_exp2f(x * 2.8853900817779268f); // e^(2x)
    return 1.f - 2.f * __builtin_amdgcn_rcpf(e + 1.f);
}
__device__ __forceinline__ void gload16(void* lds, const void* g) {
    __builtin_amdgcn_global_load_lds(
        (const __attribute__((address_space(1))) unsigned int*)g,
        (__attribute__((address_space(3))) unsigned int*)lds,
        16, 0, 0);
}

// ---- shared K-loop: BM=128, BK=64, 256 threads, 4 waves 2x2,
// double-buffered global_load_lds, 2-phase prefetch. ----
template<int BN>
__device__ __forceinline__ void kloop(const u16* __restrict__ A,
                                      const u16* __restrict__ Bt,
                                      int K, int m0, int n0, int kb, int ntiles,
                                      char* __restrict__ smem,
                                      f32x4 (&acc)[4][BN / 32])
{
    constexpr int FN = BN / 32;
    const int tid = threadIdx.x, wv = tid >> 6, lane = tid & 63;
    const int l15 = lane & 15, l4 = lane >> 4;
    const int wr = wv >> 1, wc = wv & 1;
    const int Lb = tid * 16;

    auto stage = [&](int buf, int kt) {
        char* Asb = smem + buf * 16384;
        char* Bsb = smem + 32768 + buf * (BN * 128);
#pragma unroll
        for (int q = 0; q < 4; q++) {
            int L = q * 4096 + Lb;
            int row = L >> 7, colb = L & 127;
            gload16(Asb + L, (const char*)A + ((size_t)(m0 + row) * K + kt) * 2 + colb);
        }
#pragma unroll
        for (int q = 0; q < BN / 32; q++) {
            int L = q * 4096 + Lb;
            int row = L >> 7, colb = L & 127;
            gload16(Bsb + L, (const char*)Bt + ((size_t)(n0 + row) * K + kt) * 2 + colb);
        }
    };

    stage(0, kb);
    __syncthreads();
    int buf = 0;
    for (int t = 0; t < ntiles; t++) {
        if (t + 1 < ntiles) stage(buf ^ 1, kb + (t + 1) * 64);
        const char* Asb = smem + buf * 16384;
        const char* Bsb = smem + 32768 + buf * (BN * 128);
#pragma unroll
        for (int ks = 0; ks < 2; ks++) {
            bf16x8 af[4], bfr[FN];
#pragma unroll
            for (int mi = 0; mi < 4; mi++) {
                int r = wr * 64 + mi * 16 + l15;
                af[mi] = *(const bf16x8*)(Asb + r * 128 + ((((ks << 2) | l4) ^ (r & 7)) << 4));
            }
#pragma unroll
            for (int nj = 0; nj < FN; nj++) {
                int c = wc * (FN * 16) + nj * 16 + l15;
                bfr[nj] = *(const bf16x8*)(Bsb + c * 128 + ((((ks << 2) | l4) ^ (c & 7)) << 4));
            }
#pragma unroll
            for (int mi = 0; mi < 4; mi++)
#pragma unroll
                for (int nj = 0; nj < FN; nj++)
                    acc[mi][nj] = __builtin_amdgcn_mfma_f32_16x16x32_bf16(
                        af[mi], bfr[nj], acc[mi][nj], 0, 0, 0);
        }
        __syncthreads();
        buf ^= 1;
    }
}

// MODE 0: Cb = bf16(acc)                                  (g3 / E precompute)
// MODE 1: h1=tanh(acc+bias+t*bias2)->Cb; Cb2=aux*(1-h1^2) (G1 -> h1, me; aux=E)
template<int MODE>
__global__ __launch_bounds__(256)
void mfma_gemm(const u16* __restrict__ A, int K,
               const u16* __restrict__ Bt, int N,
               u16* __restrict__ Cb,
               const float* __restrict__ bias, const float* __restrict__ bias2,
               float tval,
               const u16* __restrict__ auxb, u16* __restrict__ Cb2)
{
    __shared__ __align__(16) char smem[65536];
    const int m0 = blockIdx.y * 128, n0 = blockIdx.x * 128;
    f32x4 acc[4][4] = {};
    kloop<128>(A, Bt, K, m0, n0, 0, K / 64, smem, acc);

    const int tid = threadIdx.x, wv = tid >> 6, lane = tid & 63;
    const int l15 = lane & 15, l4 = lane >> 4;
    const int wr = wv >> 1, wc = wv & 1;
    float* ep = (float*)smem;               // [128][34]
    const int erow = tid >> 1, ehalf = tid & 1;
    const int gm = m0 + erow;
#pragma unroll
    for (int c = 0; c < 4; c++) {
        __syncthreads();
        if (wc == (c >> 1)) {
            int njb = (c & 1) * 2;
#pragma unroll
            for (int mi = 0; mi < 4; mi++)
#pragma unroll
                for (int jj = 0; jj < 2; jj++)
#pragma unroll
                    for (int r = 0; r < 4; r++) {
                        int row = wr * 64 + mi * 16 + l4 * 4 + r;
                        ep[row * 34 + jj * 16 + l15] = acc[mi][njb + jj][r];
                    }
        }
        __syncthreads();
        float v[16];
#pragma unroll
        for (int j = 0; j < 16; j++) v[j] = ep[erow * 34 + ehalf * 16 + j];
        const int kbase = n0 + c * 32 + ehalf * 16;
        const int gsb = (n0 >> 3) + c * 4 + ehalf * 2;
        const size_t idxA = swz_slot(gm, gsb, N);
        const size_t idxB = swz_slot(gm, gsb + 1, N);

        if constexpr (MODE == 0) {
            union { bf16x8 v8; u16 u[8]; } pa, pb;
#pragma unroll
            for (int j = 0; j < 8; j++) { pa.u[j] = f2bf(v[j]); pb.u[j] = f2bf(v[j + 8]); }
            *(bf16x8*)(Cb + idxA) = pa.v8;
            *(bf16x8*)(Cb + idxB) = pb.v8;
        } else {
            union { bf16x8 v8; u16 u[8]; } ha, hb, ga, gb;
            bf16x8 e0 = *(const bf16x8*)(auxb + idxA);
            bf16x8 e1 = *(const bf16x8*)(auxb + idxB);
#pragma unroll
            for (int j = 0; j < 8; j++) {
                float h0 = tanh_fast(v[j] + bias[kbase + j] + tval * bias2[kbase + j]);
                float h1v = tanh_fast(v[j + 8] + bias[kbase + 8 + j] + tval * bias2[kbase + 8 + j]);
                ha.u[j] = f2bf(h0);
                hb.u[j] = f2bf(h1v);
                ga.u[j] = f2bf(bf2f((u16)e0[j]) * (1.f - h0 * h0));
                gb.u[j] = f2bf(bf2f((u16)e1[j]) * (1.f - h1v * h1v));
            }
            *(bf16x8*)(Cb  + idxA) = ha.v8;
            *(bf16x8*)(Cb  + idxB) = hb.v8;
            *(bf16x8*)(Cb2 + idxA) = ga.v8;
            *(bf16x8*)(Cb2 + idxB) = gb.v8;
        }
    }
}

// ---- G2 dual + G3 partial: one w2t pass, two accumulators; h2 stays in LDS;
// epilogue also computes dx split-K partial = h2tile @ W3[n0:n0+128,:].
// XCD-aware bid remap: bid%8 = HW XCD; each XCD owns 8 m-strips x 8 n-blocks
// so h1/me tiles are L2-coalesced across that XCD's concurrent blocks.
__global__ __launch_bounds__(512)
void gemm_dual(const u16* __restrict__ h1, const u16* __restrict__ me,
               const u16* __restrict__ w2t, const u16* __restrict__ g3,
               const float* __restrict__ b2, const u16* __restrict__ w3tb,
               float* __restrict__ trp, float* __restrict__ part3)
{
    __shared__ __align__(16) char smem[98304];   // A1[2]16K | A2[2]16K | B[2]16K
    const int tid = threadIdx.x, wv = tid >> 6, lane = tid & 63;
    const int l15 = lane & 15, l4 = lane >> 4;
    const int wr = wv >> 2, wc = wv & 3;         // 8 waves: 2M x 4N
    const int bid = blockIdx.x;
    const int midx = (bid & 7) * 8 + ((bid >> 3) & 7);  // m-strip 0..63
    const int nidx = bid >> 6;                          // n-block 0..7
    const int m0 = midx * 128, n0 = nidx * 128;
    const int Lb = tid * 16;

    auto stage = [&](int buf, int kt) {
        char* A1s = smem + buf * 16384;
        char* A2s = smem + 32768 + buf * 16384;
        char* Bs  = smem + 65536 + buf * 16384;
#pragma unroll
        for (int q = 0; q < 2; q++) {
            int L = q * 8192 + Lb;
            int row = L >> 7, colb = L & 127;
            gload16(A1s + L, (const char*)h1 + ((size_t)(m0 + row) * HID + kt) * 2 + colb);
            gload16(A2s + L, (const char*)me + ((size_t)(m0 + row) * HID + kt) * 2 + colb);
            gload16(Bs + L, (const char*)w2t + ((size_t)(n0 + row) * HID + kt) * 2 + colb);
        }
    };

    f32x4 acc2[4][2] = {}, acc5[4][2] = {};
    stage(0, 0);
    __syncthreads();
    int buf = 0;
    for (int t = 0; t < 16; t++) {
        if (t + 1 < 16) stage(buf ^ 1, (t + 1) * 64);
        const char* A1s = smem + buf * 16384;
        const char* A2s = smem + 32768 + buf * 16384;
        const char* Bs  = smem + 65536 + buf * 16384;
#pragma unroll
        for (int ks = 0; ks < 2; ks++) {
            bf16x8 a1f[4], a2f[4], bfr[2];
#pragma unroll
            for (int mi = 0; mi < 4; mi++) {
                int r = wr * 64 + mi * 16 + l15;
                int off = r * 128 + ((((ks << 2) | l4) ^ (r & 7)) << 4);
                a1f[mi] = *(const bf16x8*)(A1s + off);
                a2f[mi] = *(const bf16x8*)(A2s + off);
            }
#pragma unroll
            for (int nj = 0; nj < 2; nj++) {
                int c = wc * 32 + nj * 16 + l15;
                bfr[nj] = *(const bf16x8*)(Bs + c * 128 + ((((ks << 2) | l4) ^ (c & 7)) << 4));
            }
#pragma unroll
            for (int mi = 0; mi < 4; mi++)
#pragma unroll
                for (int nj = 0; nj < 2; nj++) {
                    acc2[mi][nj] = __builtin_amdgcn_mfma_f32_16x16x32_bf16(
                        a1f[mi], bfr[nj], acc2[mi][nj], 0, 0, 0);
                    acc5[mi][nj] = __builtin_amdgcn_mfma_f32_16x16x32_bf16(
                        a2f[mi], bfr[nj], acc5[mi][nj], 0, 0, 0);
                }
        }
        __syncthreads();
        buf ^= 1;
    }

    // ---- epilogue: LDS roundtrip; h2 -> swizzled LDS (not global) ----
    float* ep2 = (float*)smem;                  // [128][34]
    float* ep5 = (float*)(smem + 17408);        // [128][34]
    float* red = (float*)(smem + 34816);        // [128][4]
    char*  hts = smem + 36864;                  // h2 tile [128][128] bf16 swz
    const int erow = tid >> 2, esq = tid & 3;
    const int gm = m0 + erow;
    float tsum = 0.f;
#pragma unroll
    for (int c = 0; c < 4; c++) {
        __syncthreads();
        if (wc == c) {
#pragma unroll
            for (int mi = 0; mi < 4; mi++)
#pragma unroll
                for (int nj = 0; nj < 2; nj++)
#pragma unroll
                    for (int r = 0; r < 4; r++) {
                        int row = wr * 64 + mi * 16 + l4 * 4 + r;
                        ep2[row * 34 + nj * 16 + l15] = acc2[mi][nj][r];
                        ep5[row * 34 + nj * 16 + l15] = acc5[mi][nj][r];
                    }
        }
        __syncthreads();
        float v2[8], v5[8];
#pragma unroll
        for (int j = 0; j < 8; j++) {
            v2[j] = ep2[erow * 34 + esq * 8 + j];
            v5[j] = ep5[erow * 34 + esq * 8 + j];
        }
        const int cb = n0 + c * 32 + esq * 8;
        const int gs = (n0 >> 3) + c * 4 + esq;
        const size_t idx = swz_slot(gm, gs, HID);
        bf16x8 g3v = *(const bf16x8*)(g3 + idx);
        union { bf16x8 v8; u16 u[8]; } hw;
#pragma unroll
        for (int j = 0; j < 8; j++) {
            float hv = tanh_fast(v2[j] + b2[cb + j]);
            hw.u[j] = f2bf(hv);
            tsum += v5[j] * bf2f((u16)g3v[j]) * (1.f - hv * hv);
        }
        const int slot = c * 4 + esq;  // 0..15 within 128-el row
        *(bf16x8*)(hts + erow * 256 + (((slot & 8) | ((slot & 7) ^ (erow & 7))) << 4)) = hw.v8;
    }
    red[erow * 4 + esq] = tsum;
    __syncthreads();
    if (tid < 128)
        trp[(size_t)nidx * BATCH + m0 + tid] =
            red[tid * 4] + red[tid * 4 + 1] + red[tid * 4 + 2] + red[tid * 4 + 3];

    // ---- G3 split-K partial: part3[nidx] = h2tile @ W3[n0:n0+128, 0:64] ----
    {
        const int wm = wv >> 2, wf = wv & 3;    // 2 x 4 (M64 x F16 per wave)
        f32x4 accd[4] = {};
#pragma unroll
        for (int ks = 0; ks < 4; ks++) {
            const int frow = wf * 16 + l15;
            bf16x8 bfrag = *(const bf16x8*)(w3tb + swz_off(frow, n0 + ks * 32 + l4 * 8, HID));
#pragma unroll
            for (int mi = 0; mi < 4; mi++) {
                int r = wm * 64 + mi * 16 + l15;
                int slot = ks * 4 + l4;
                bf16x8 afrag = *(const bf16x8*)(hts + r * 256
                                 + (((slot & 8) | ((slot & 7) ^ (r & 7))) << 4));
                accd[mi] = __builtin_amdgcn_mfma_f32_16x16x32_bf16(
                    afrag, bfrag, accd[mi], 0, 0, 0);
            }
        }
#pragma unroll
        for (int mi = 0; mi < 4; mi++)
#pragma unroll
            for (int q = 0; q < 4; q++) {
                int gmr = m0 + wm * 64 + mi * 16 + l4 * 4 + q;
                int gf = wf * 16 + l15;
                part3[(size_t)nidx * (BATCH * 64) + (size_t)gmr * 64 + gf] = accd[mi][q];
            }
    }
}

// ---- RK4 combine (elementwise): sum 8 dx partials + b3, advance state ----
__global__ void rk4_combine(const float* __restrict__ part3, const float* __restrict__ b3,
                            const float* __restrict__ trpart,
                            float* __restrict__ yx, float* __restrict__ yld,
                            float* __restrict__ accx, float* __restrict__ accld,
                            u16* __restrict__ xin_bf, float* __restrict__ outp,
                            float wacc, float wtmp, int first, int fin, int last,
                            float h6)
{
    int i = blockIdx.x * 256 + threadIdx.x;
    if (i < BATCH * FEAT) {
        int f = i & 63, m = i >> 6;
        float d = b3[f];
#pragma unroll
        for (int nb = 0; nb < 8; nb++) d += part3[(size_t)nb * (BATCH * 64) + i];
        float a = (first ? 0.f : accx[i]) + wacc * d;
        accx[i] = a;
        float nx;
        if (fin) { nx = yx[i] + h6 * a; yx[i] = nx; }
        else     { nx = yx[i] + wtmp * d; }
        if (last) outp[i] = nx;
        else      xin_bf[swz_off(m, f, 64)] = f2bf(nx);
    } else if (i < BATCH * FEAT + BATCH) {
        int m = i - BATCH * FEAT;
        float tr = 0.f;
#pragma unroll
        for (int nb = 0; nb < 8; nb++) tr += trpart[(size_t)nb * BATCH + m];
        float a = (first ? 0.f : accld[m]) + wacc * (-tr);
        accld[m] = a;
        if (fin) {
            float nl = yld[m] + h6 * a;
            yld[m] = nl;
            if (last) outp[(size_t)BATCH * 64 + m] = nl;
        }
    }
}

__global__ void init_state(const float* __restrict__ x,
                           float* __restrict__ yx, u16* __restrict__ xin_bf,
                           float* __restrict__ yld)
{
    int i = blockIdx.x * 256 + threadIdx.x;
    if (i < BATCH * FEAT) {
        float v = x[i];
        yx[i] = v;
        xin_bf[swz_off(i >> 6, i & 63, 64)] = f2bf(v);
    }
    if (i < BATCH) yld[i] = 0.f;
}

__global__ void cast_bf(const float* __restrict__ in, u16* __restrict__ out,
                        int n, int W)
{
    int i = blockIdx.x * 256 + threadIdx.x;
    if (i < n) out[swz_off(i / W, i % W, W)] = f2bf(in[i]);
}

// in [R'][C'] fp32 -> out [C'][R'] bf16 swizzled
__global__ void transpose_cast(const float* __restrict__ in, u16* __restrict__ out,
                               int R, int C)
{
    __shared__ float t[32][33];
    int bx = blockIdx.x * 32, by = blockIdx.y * 32;
    int tx = threadIdx.x, ty = threadIdx.y;  // block (32,8)
    for (int i = 0; i < 32; i += 8)
        t[ty + i][tx] = in[(size_t)(by + ty + i) * C + bx + tx];
    __syncthreads();
    for (int i = 0; i < 32; i += 8)
        out[swz_off(bx + ty + i, by + tx, R)] = f2bf(t[tx][ty + i]);
}

extern "C" void kernel_launch(void* const* d_in, const int* in_sizes, int n_in,
                              void* d_out, int out_size, void* d_ws, size_t ws_size,
                              hipStream_t stream)
{
    const float* x   = (const float*)d_in[0];
    const float* W1  = (const float*)d_in[1];
    const float* b1  = (const float*)d_in[2];
    const float* W2  = (const float*)d_in[3];
    const float* b2  = (const float*)d_in[4];
    const float* W3  = (const float*)d_in[5];
    const float* b3  = (const float*)d_in[6];
    const float* eps = (const float*)d_in[7];
    float* out = (float*)d_out;

    char* ws = (char*)d_ws;
    size_t o = 0;
    auto alloc = [&](size_t bytes) { char* p = ws + o; o += (bytes + 255) & ~(size_t)255; return p; };

    float* yx     = (float*)alloc((size_t)BATCH * FEAT * 4);
    float* yld    = (float*)alloc(BATCH * 4);
    float* accx   = (float*)alloc((size_t)BATCH * FEAT * 4);
    float* accld  = (float*)alloc(BATCH * 4);
    float* trpart = (float*)alloc((size_t)8 * BATCH * 4);
    float* part3  = (float*)alloc((size_t)8 * BATCH * FEAT * 4);
    u16* xin_bf   = (u16*)alloc((size_t)BATCH * FEAT * 2);
    u16* h1       = (u16*)alloc((size_t)BATCH * HID * 2);
    u16* me       = (u16*)alloc((size_t)BATCH * HID * 2);
    u16* g3       = (u16*)alloc((size_t)BATCH * HID * 2);
    u16* E_bf     = (u16*)alloc((size_t)BATCH * HID * 2);
    u16* eps_bf   = (u16*)alloc((size_t)BATCH * FEAT * 2);
    u16* w1tb     = (u16*)alloc((size_t)HID * FEAT * 2);   // [1024][64] W1[:64]^T
    u16* w2t      = (u16*)alloc((size_t)HID * HID * 2);    // W2^T
    u16* w3_bf    = (u16*)alloc((size_t)HID * FEAT * 2);   // [1024][64] W3
    u16* w3t      = (u16*)alloc((size_t)FEAT * HID * 2);   // [64][1024] W3^T

    const dim3 blk(256);
    const dim3 gBig(HID / 128, BATCH / 128);   // (8, 64)
    const int combN = (BATCH * FEAT + BATCH + 255) / 256;

    // ---- setup (every call; deterministic) ----
    init_state<<<dim3((BATCH * FEAT + 255) / 256), blk, 0, stream>>>(x, yx, xin_bf, yld);
    cast_bf<<<dim3((HID * FEAT + 255) / 256), blk, 0, stream>>>(W3, w3_bf, HID * FEAT, FEAT);
    cast_bf<<<dim3((BATCH * FEAT + 255) / 256), blk, 0, stream>>>(eps, eps_bf, BATCH * FEAT, FEAT);
    transpose_cast<<<dim3(HID / 32, HID / 32), dim3(32, 8), 0, stream>>>(W2, w2t, HID, HID);
    transpose_cast<<<dim3(HID / 32, FEAT / 32), dim3(32, 8), 0, stream>>>(W1, w1tb, FEAT, HID);
    transpose_cast<<<dim3(FEAT / 32, HID / 32), dim3(32, 8), 0, stream>>>(W3, w3t, HID, FEAT);
    // g3 = eps @ W3^T ; E = eps @ W1[:64]   (constant across evals)
    mfma_gemm<0><<<gBig, blk, 0, stream>>>(eps_bf, FEAT, w3_bf, HID,
                                           g3, nullptr, nullptr, 0.f, nullptr, nullptr);
    mfma_gemm<0><<<gBig, blk, 0, stream>>>(eps_bf, FEAT, w1tb, HID,
                                           E_bf, nullptr, nullptr, 0.f, nullptr, nullptr);

    const float h = 1.0f / NSTEPS;
    const float cs[4] = {0.f, 0.5f, 0.5f, 1.f};

    for (int s = 0; s < NSTEPS; s++) {
        float t0 = s * h;
        for (int st = 0; st < 4; st++) {
            float ts = t0 + cs[st] * h;
            // G1: h1 = tanh(xin@W1 + b1 + t*w1x); me = (1-h1^2)*E
            mfma_gemm<1><<<gBig, blk, 0, stream>>>(xin_bf, FEAT, w1tb, HID,
                                                   h1, b1, W1 + (size_t)FEAT * HID, ts,
                                                   E_bf, me);
            // G2 dual + G3 partial: trpart + part3 (h2 never leaves LDS)
            gemm_dual<<<dim3(512), dim3(512), 0, stream>>>(h1, me, w2t, g3, b2, w3t,
                                                           trpart, part3);
            // RK4 combine (elementwise)
            float wacc = (st == 1 || st == 2) ? 2.f : 1.f;
            float wtmp = (st == 0 || st == 1) ? h * 0.5f : h;
            rk4_combine<<<dim3(combN), blk, 0, stream>>>(part3, b3, trpart,
                                                         yx, yld, accx, accld,
                                                         xin_bf, out,
                                                         wacc, wtmp,
                                                         (st == 0) ? 1 : 0,
                                                         (st == 3) ? 1 : 0,
                                                         (s == NSTEPS - 1 && st == 3) ? 1 : 0,
                                                         h / 6.f);
        }
    }
}